// Round 1
// baseline (52.008 us; speedup 1.0000x reference)
//
#include <hip/hip_runtime.h>

// Output: K (1, 8192, 8192) f32 = 256 MB. Memory-bound on the write stream.
// Each thread handles one i and a pair of j's -> a 2x4 f32 patch,
// written as two coalesced float4 stores (rows 2i and 2i+1).

__global__ void __launch_bounds__(256) rbf_divfree_kernel(
    const float* __restrict__ X,        // (n, 2)
    const float* __restrict__ Y,        // (m, 2)
    const float* __restrict__ lls,      // (1,)
    float* __restrict__ out,            // (2n, 2m) row-major
    int n, int mp)                      // mp = m/2 (j-pairs per row)
{
    const float inv_ls = expf(-lls[0]);          // 1/ls, exact for lls=0
    const size_t ldc = (size_t)mp * 4;           // output row stride = 2m
    const int total = n * mp;
    const int stride = gridDim.x * blockDim.x;

    for (int idx = blockIdx.x * blockDim.x + threadIdx.x; idx < total; idx += stride) {
        const int i  = idx / mp;
        const int jp = idx - i * mp;             // j-pair index; j0 = 2*jp

        const float xi0 = X[2 * i];
        const float xi1 = X[2 * i + 1];
        // Y[j0] and Y[j0+1] as one 16B load
        const float4 y = *reinterpret_cast<const float4*>(Y + 4 * (size_t)jp);

        float4 row0, row1;
        {   // j = j0  (y.x, y.y)
            const float dx = xi0 - y.x;
            const float dy = xi1 - y.y;
            const float t  = (dx * dx + dy * dy) * inv_ls;   // dist/ls
            const float ke = expf(-0.5f * t);                // SIGMA_VAR = 1
            const float c  = 1.0f - t;                       // (d-1) - dist/ls
            row0.x = (dx * dx * inv_ls + c) * ke;            // A00
            row0.y = (dx * dy * inv_ls) * ke;                // A01
            row1.x = row0.y;                                 // A10
            row1.y = (dy * dy * inv_ls + c) * ke;            // A11
        }
        {   // j = j0+1  (y.z, y.w)
            const float dx = xi0 - y.z;
            const float dy = xi1 - y.w;
            const float t  = (dx * dx + dy * dy) * inv_ls;
            const float ke = expf(-0.5f * t);
            const float c  = 1.0f - t;
            row0.z = (dx * dx * inv_ls + c) * ke;
            row0.w = (dx * dy * inv_ls) * ke;
            row1.z = row0.w;
            row1.w = (dy * dy * inv_ls + c) * ke;
        }

        float* p0 = out + (size_t)(2 * i) * ldc + 4 * (size_t)jp;
        *reinterpret_cast<float4*>(p0)       = row0;   // row 2i,   cols 4jp..4jp+3
        *reinterpret_cast<float4*>(p0 + ldc) = row1;   // row 2i+1, cols 4jp..4jp+3
    }
}

extern "C" void kernel_launch(void* const* d_in, const int* in_sizes, int n_in,
                              void* d_out, int out_size, void* d_ws, size_t ws_size,
                              hipStream_t stream) {
    const float* X   = (const float*)d_in[0];
    const float* Y   = (const float*)d_in[1];
    const float* lls = (const float*)d_in[2];
    float* out = (float*)d_out;

    const int n  = in_sizes[0] / 2;   // 4096
    const int m  = in_sizes[1] / 2;   // 4096
    const int mp = m / 2;             // 2048 j-pairs

    const int total   = n * mp;       // 8.4M threads' worth of patches
    const int block   = 256;
    int grid = (total + block - 1) / block;
    if (grid > 2048) grid = 2048;     // grid-stride; ~8 blocks/CU

    rbf_divfree_kernel<<<grid, block, 0, stream>>>(X, Y, lls, out, n, mp);
}

// Round 3
// 45.982 us; speedup vs baseline: 1.1311x; 1.1311x over previous
//
#include <hip/hip_runtime.h>

// Output: K (8192, 8192) f32 = 256 MB. Pure write-stream bound.
// 2D launch: blockIdx.y = i (row pair), x covers jp (j-pairs).
// Each thread: one 2x4 f32 patch -> two nontemporal 16B stores.

typedef float v4f __attribute__((ext_vector_type(4)));

__global__ void __launch_bounds__(256) rbf_divfree_kernel(
    const float* __restrict__ X,        // (n, 2)
    const float* __restrict__ Y,        // (m, 2)
    const float* __restrict__ lls,      // (1,)
    float* __restrict__ out,            // (2n, 2m) row-major
    int mp)                             // mp = m/2 (j-pairs per row)
{
    const int jp = blockIdx.x * blockDim.x + threadIdx.x;
    if (jp >= mp) return;
    const int i = blockIdx.y;

    const float inv_ls = __expf(-lls[0]);        // 1/ls
    const size_t ldc = (size_t)mp * 4;           // output row stride = 2m

    const float xi0 = X[2 * i];
    const float xi1 = X[2 * i + 1];
    const v4f y = *reinterpret_cast<const v4f*>(Y + 4 * (size_t)jp);

    v4f row0, row1;
    {   // j = 2*jp  (y[0], y[1])
        const float dx = xi0 - y[0];
        const float dy = xi1 - y[1];
        const float t  = (dx * dx + dy * dy) * inv_ls;   // dist/ls
        const float ke = __expf(-0.5f * t);              // SIGMA_VAR = 1
        const float c  = 1.0f - t;                       // (d-1) - dist/ls
        row0[0] = (dx * dx * inv_ls + c) * ke;           // A00
        row0[1] = (dx * dy * inv_ls) * ke;               // A01
        row1[0] = row0[1];                               // A10
        row1[1] = (dy * dy * inv_ls + c) * ke;           // A11
    }
    {   // j = 2*jp+1  (y[2], y[3])
        const float dx = xi0 - y[2];
        const float dy = xi1 - y[3];
        const float t  = (dx * dx + dy * dy) * inv_ls;
        const float ke = __expf(-0.5f * t);
        const float c  = 1.0f - t;
        row0[2] = (dx * dx * inv_ls + c) * ke;
        row0[3] = (dx * dy * inv_ls) * ke;
        row1[2] = row0[3];
        row1[3] = (dy * dy * inv_ls + c) * ke;
    }

    float* p0 = out + (size_t)(2 * i) * ldc + 4 * (size_t)jp;
    __builtin_nontemporal_store(row0, reinterpret_cast<v4f*>(p0));
    __builtin_nontemporal_store(row1, reinterpret_cast<v4f*>(p0 + ldc));
}

extern "C" void kernel_launch(void* const* d_in, const int* in_sizes, int n_in,
                              void* d_out, int out_size, void* d_ws, size_t ws_size,
                              hipStream_t stream) {
    const float* X   = (const float*)d_in[0];
    const float* Y   = (const float*)d_in[1];
    const float* lls = (const float*)d_in[2];
    float* out = (float*)d_out;

    const int n  = in_sizes[0] / 2;   // 4096
    const int m  = in_sizes[1] / 2;   // 4096
    const int mp = m / 2;             // 2048 j-pairs

    const int block = 256;
    dim3 grid((mp + block - 1) / block, n);   // (8, 4096)

    rbf_divfree_kernel<<<grid, block, 0, stream>>>(X, Y, lls, out, mp);
}